// Round 1
// 290.980 us; speedup vs baseline: 1.0004x; 1.0004x over previous
//
#include <hip/hip_runtime.h>

// Pillar scatter, gather-formulated with per-row binning:
//   out[b, f, y, x] = sum of pillars[b,p,:] over active pillars p at (y,x).
// Output [4, 64, 512, 512] fp32 (268 MB) -- every element written exactly once
// by fill_out (no d_out memset needed).
//
// Pass 1 (bin): active pillars appended to per-(b,y) row lists (atomicAdd on
//   2048 counters). Row overflow (>ROWCAP, never in practice) -> global list.
// Pass 2 (fill): one block per (b,y) row. Branchless emit: xmap points empty
//   cells at a zeroed dummy LDS row (broadcast read, no cndmask). 3 barriers.
//   float4 staging of pillar rows, stride-68 padding (16B-aligned, <=2-way
//   banks). Nontemporal float4 stores, strength-reduced plane pointer.
// Pass 3 (fixup): atomicAdd the (normally zero) overflow entries.

#define NF 64
#define XS 512
#define YS 512
#define ROWCAP 64            // max pillars staged per (b,y) row; mean ~12
#define DUMMY ROWCAP         // xmap sentinel -> zeroed dummy row in prow
#define PSTRIDE 68           // floats per staged row: 64 + 4 pad (16B aligned)
#define OVCAP 16384

typedef float vf4 __attribute__((ext_vector_type(4)));  // native vec for nontemporal

__global__ void __launch_bounds__(256) bin_pillars(
    const int* __restrict__ coord,
    const int* __restrict__ contains,
    int* __restrict__ rowcnt,
    int* __restrict__ rowlist,
    int* __restrict__ ovcnt,
    int* __restrict__ ovlist,
    int BP, int P) {
  int gid = blockIdx.x * 256 + threadIdx.x;
  if (gid >= BP) return;
  if (contains[gid] == 0) return;
  int y = coord[gid * 3 + 1];
  int x = coord[gid * 3 + 2];
  int b = gid / P;
  int by = (b << 9) | y;
  int k = atomicAdd(rowcnt + by, 1);
  if (k < ROWCAP) {
    rowlist[by * ROWCAP + k] = (x << 16) | gid;   // gid < 48000 fits 16 bits
  } else {
    int o = atomicAdd(ovcnt, 1);
    if (o < OVCAP) ovlist[o] = gid;
  }
}

__global__ void __launch_bounds__(256) fill_out(
    const float* __restrict__ pillars,
    const int* __restrict__ rowcnt,
    const int* __restrict__ rowlist,
    float* __restrict__ out) {
  int by = blockIdx.x;            // [0, B*YS)
  int b = by >> 9;
  int y = by & 511;
  __shared__ int xmap[XS];                       // x -> staged row idx, or DUMMY
  __shared__ float prow[(ROWCAP + 1) * PSTRIDE]; // staged rows + zeroed dummy row

  int t = threadIdx.x;

  // issue the dependent global loads as early as possible
  int n = rowcnt[by];
  int e = 0;
  if (t < ROWCAP) e = rowlist[by * ROWCAP + t];  // beyond-count entries unused

  xmap[t] = DUMMY;
  xmap[t + 256] = DUMMY;
  if (t < NF) prow[DUMMY * PSTRIDE + t] = 0.f;   // dummy zero row
  __syncthreads();

  if (n > ROWCAP) n = ROWCAP;

  // claim cells; CAS losers are duplicate-cell pillars -> merged below.
  int myold = DUMMY;
  if (t < n) {
    int x = e >> 16;
    myold = atomicCAS(&xmap[x], DUMMY, t);       // DUMMY means winner
  }

  // stage listed pillar rows as float4 (4 rows per wave-iteration)
  int k = t >> 4, c = t & 15;
  for (; k < n; k += 16) {
    int g = rowlist[by * ROWCAP + k] & 0xFFFF;
    vf4 v = ((const vf4*)pillars)[(g << 4) + c]; // 256B contiguous per row
    *(vf4*)&prow[k * PSTRIDE + (c << 2)] = v;
  }
  __syncthreads();

  // merge duplicate cells into the winner's staged row (rare: ~0.13/row)
  if (myold != DUMMY) {
    for (int f = 0; f < NF; ++f)
      atomicAdd(&prow[myold * PSTRIDE + f], prow[t * PSTRIDE + f]);
  }
  __syncthreads();

  // emit: 128 float4 x-positions x 64 feature planes, branchless
  int x4 = (t & 127) << 2;
  int fbase = t >> 7;                            // 0 or 1
  int s0 = xmap[x4 + 0] * PSTRIDE;
  int s1 = xmap[x4 + 1] * PSTRIDE;
  int s2 = xmap[x4 + 2] * PSTRIDE;
  int s3 = xmap[x4 + 3] * PSTRIDE;
  float* po = out + (((size_t)(b * NF + fbase)) << 18) + ((size_t)y << 9) + x4;
#pragma unroll 8
  for (int fi = 0; fi < 32; ++fi) {
    int f = fi * 2 + fbase;
    vf4 v;
    v.x = prow[s0 + f];
    v.y = prow[s1 + f];
    v.z = prow[s2 + f];
    v.w = prow[s3 + f];
    __builtin_nontemporal_store(v, (vf4*)po);
    po += (size_t)2 << 18;                       // advance 2 feature planes
  }
}

__global__ void __launch_bounds__(256) fixup_overflow(
    const float* __restrict__ pillars,
    const int* __restrict__ coord,
    const int* __restrict__ ovlist,
    const int* __restrict__ ovcnt,
    float* __restrict__ out,
    int P) {
  int gid = blockIdx.x * 256 + threadIdx.x;
  int w = gid >> 6;
  int lane = gid & 63;
  int n = *ovcnt;
  if (n > OVCAP) n = OVCAP;
  int nw = gridDim.x * 4;   // total waves
  for (int i = w; i < n; i += nw) {
    int g = ovlist[i];
    int y = coord[g * 3 + 1];
    int x = coord[g * 3 + 2];
    int b = g / P;
    atomicAdd(out + (((size_t)(b * NF + lane)) << 18) + ((size_t)y << 9) + x,
              pillars[((size_t)g << 6) + lane]);
  }
}

extern "C" void kernel_launch(void* const* d_in, const int* in_sizes, int n_in,
                              void* d_out, int out_size, void* d_ws, size_t ws_size,
                              hipStream_t stream) {
  const float* pillars  = (const float*)d_in[0];
  const int*   coord    = (const int*)d_in[1];
  const int*   contains = (const int*)d_in[2];
  float* out = (float*)d_out;

  const int BP = in_sizes[2];                    // B * P = 48000
  const int B  = out_size / (NF * XS * YS);      // 4
  const int P  = BP / B;                         // 12000
  const int NROW = B * YS;                       // 2048

  // workspace layout: [rowcnt 2048 ints][ovcnt 1 int + pad][rowlist][ovlist]
  int* rowcnt  = (int*)d_ws;
  int* ovcnt   = rowcnt + NROW;
  int* rowlist = ovcnt + 4;
  int* ovlist  = rowlist + NROW * ROWCAP;

  // one small clear covers rowcnt + ovcnt
  (void)hipMemsetAsync(rowcnt, 0, (size_t)(NROW + 4) * sizeof(int), stream);

  bin_pillars<<<(BP + 255) / 256, 256, 0, stream>>>(coord, contains, rowcnt,
                                                    rowlist, ovcnt, ovlist, BP, P);
  fill_out<<<NROW, 256, 0, stream>>>(pillars, rowcnt, rowlist, out);
  fixup_overflow<<<64, 256, 0, stream>>>(pillars, coord, ovlist, ovcnt, out, P);
}